// Round 1
// baseline (29071.555 us; speedup 1.0000x reference)
//
#include <hip/hip_runtime.h>

typedef __attribute__((ext_vector_type(8))) short short8;
typedef __attribute__((ext_vector_type(4))) float f32x4;

#define WS_ALIGN(x) (((x) + 255) & ~(size_t)255)

__device__ __forceinline__ unsigned short f2bf_rne(float f) {
  union { float f; unsigned u; } v; v.f = f;
  unsigned r = v.u + 0x7fffu + ((v.u >> 16) & 1u);
  return (unsigned short)(r >> 16);
}

// ---------------- conversion: f32 -> (hi bf16, lo bf16) split ----------------
__global__ __launch_bounds__(256) void k_split_bf16(const float* __restrict__ in,
                                                    unsigned short* __restrict__ hi,
                                                    unsigned short* __restrict__ lo, size_t n) {
  size_t i = (size_t)blockIdx.x * 256 + threadIdx.x;
  size_t stride = (size_t)gridDim.x * 256;
  for (; i < n; i += stride) {
    float x = in[i];
    unsigned short h = f2bf_rne(x);
    union { unsigned u; float f; } hv; hv.u = (unsigned)h << 16;
    hi[i] = h;
    lo[i] = f2bf_rne(x - hv.f);
  }
}

__global__ void k_concat2(const float* __restrict__ a, const float* __restrict__ b,
                          int na, int nb, float* __restrict__ o) {
  int i = blockIdx.x * 256 + threadIdx.x;
  if (i < na) o[i] = a[i];
  else if (i < na + nb) o[i] = b[i - na];
}

// ---------------- split-bf16 MFMA GEMM: C[m][n] = sum_k A[m][k]*B[n][k] + bias[n] ----------------
__global__ __launch_bounds__(256) void k_gemm_split(
    const unsigned short* __restrict__ Ah, const unsigned short* __restrict__ Al,
    const unsigned short* __restrict__ Bh, const unsigned short* __restrict__ Bl,
    const float* __restrict__ bias, float* __restrict__ C,
    int M, int N, int K) {
  __shared__ __align__(16) unsigned short sAh[128][40];
  __shared__ __align__(16) unsigned short sAl[128][40];
  __shared__ __align__(16) unsigned short sBh[128][40];
  __shared__ __align__(16) unsigned short sBl[128][40];
  int bm = blockIdx.x, bn = blockIdx.y;
  int tid = threadIdx.x;
  int lane = tid & 63, wave = tid >> 6;
  int wm = wave >> 1, wn = wave & 1;
  int lr = lane & 15, lk = (lane >> 4) * 8;
  f32x4 acc[4][4] = {};
  for (int k0 = 0; k0 < K; k0 += 32) {
    __syncthreads();
#pragma unroll
    for (int i = 0; i < 2; ++i) {
      int q = tid + i * 256;
      int row = q >> 2, c8 = (q & 3) * 8;
      size_t ga = (size_t)(bm * 128 + row) * K + k0 + c8;
      size_t gb = (size_t)(bn * 128 + row) * K + k0 + c8;
      *(short8*)&sAh[row][c8] = *(const short8*)(Ah + ga);
      *(short8*)&sAl[row][c8] = *(const short8*)(Al + ga);
      *(short8*)&sBh[row][c8] = *(const short8*)(Bh + gb);
      *(short8*)&sBl[row][c8] = *(const short8*)(Bl + gb);
    }
    __syncthreads();
    short8 ah[4], al[4], bh[4], bl[4];
#pragma unroll
    for (int x = 0; x < 4; ++x) {
      ah[x] = *(const short8*)&sAh[wm * 64 + x * 16 + lr][lk];
      al[x] = *(const short8*)&sAl[wm * 64 + x * 16 + lr][lk];
      bh[x] = *(const short8*)&sBh[wn * 64 + x * 16 + lr][lk];
      bl[x] = *(const short8*)&sBl[wn * 64 + x * 16 + lr][lk];
    }
#pragma unroll
    for (int mi = 0; mi < 4; ++mi)
#pragma unroll
      for (int ni = 0; ni < 4; ++ni) {
        acc[mi][ni] = __builtin_amdgcn_mfma_f32_16x16x32_bf16(ah[mi], bh[ni], acc[mi][ni], 0, 0, 0);
        acc[mi][ni] = __builtin_amdgcn_mfma_f32_16x16x32_bf16(ah[mi], bl[ni], acc[mi][ni], 0, 0, 0);
        acc[mi][ni] = __builtin_amdgcn_mfma_f32_16x16x32_bf16(al[mi], bh[ni], acc[mi][ni], 0, 0, 0);
      }
  }
#pragma unroll
  for (int mi = 0; mi < 4; ++mi)
#pragma unroll
    for (int ni = 0; ni < 4; ++ni) {
      int r0 = bm * 128 + wm * 64 + mi * 16 + (lane >> 4) * 4;
      int c = bn * 128 + wn * 64 + ni * 16 + lr;
      float bv = bias[c];
#pragma unroll
      for (int r = 0; r < 4; ++r)
        C[(size_t)(r0 + r) * N + c] = acc[mi][ni][r] + bv;
    }
}

// ---------------- LSTM recurrence (both directions in one launch) ----------------
// grid = 2*NWG blocks of 256 threads; WG w of direction d owns hidden units [w*16, w*16+16).
// Weights held in VGPRs (CPT fp32 per thread). h exchanged via global double buffer
// with agent-scope atomics + monotonic arrival counter.
template <int HD>
__global__ __launch_bounds__(256) void k_lstm_rec(
    const float* __restrict__ gx, int gxs,
    const float* __restrict__ Whh_f, const float* __restrict__ Whh_b,
    const float* __restrict__ h0, const float* __restrict__ c0,
    float* __restrict__ out, int os,
    float* hbuf, unsigned* ctr, int T, int NWG) {
  constexpr int CPT = HD / 4;
  int tid = threadIdx.x;
  int wg = blockIdx.x;
  int dir = (wg >= NWG) ? 1 : 0;
  int w = wg - dir * NWG;
  int rl = tid & 63;
  int gate = rl >> 4, jl = rl & 15;
  int chunk = tid >> 6;
  const float* Whh = dir ? Whh_b : Whh_f;

  float wreg[CPT];
  {
    const float* wp = Whh + (size_t)(gate * HD + w * 16 + jl) * HD + chunk * CPT;
#pragma unroll
    for (int k = 0; k < CPT; k += 4) {
      float4 v = *(const float4*)(wp + k);
      wreg[k] = v.x; wreg[k + 1] = v.y; wreg[k + 2] = v.z; wreg[k + 3] = v.w;
    }
  }

  __shared__ __align__(16) float h_lds[HD];
  __shared__ float part[4][64];

  float cst = 0.f;
  float* hb0 = hbuf + (size_t)dir * 2 * HD;
  if (tid < 16) {
    cst = c0[dir * HD + w * 16 + tid];
    __hip_atomic_store(&hb0[w * 16 + tid], h0[dir * HD + w * 16 + tid],
                       __ATOMIC_RELAXED, __HIP_MEMORY_SCOPE_AGENT);
  }
  __syncthreads();
  if (tid == 0)
    __hip_atomic_fetch_add(&ctr[dir], 1u, __ATOMIC_RELEASE, __HIP_MEMORY_SCOPE_AGENT);

  unsigned target = (unsigned)NWG;
  for (int ti = 0; ti < T; ++ti) {
    int t = dir ? (T - 1 - ti) : ti;
    int p = ti & 1;
    float gxv = 0.f;
    if (tid < 64)
      gxv = gx[(size_t)t * gxs + dir * 4 * HD + gate * HD + w * 16 + jl];
    if (tid == 0) {
      while (__hip_atomic_load(&ctr[dir], __ATOMIC_ACQUIRE, __HIP_MEMORY_SCOPE_AGENT) < target) {}
    }
    __syncthreads();
    const float* hsrc = hb0 + (size_t)p * HD;
    for (int i = tid; i < HD; i += 256)
      h_lds[i] = __hip_atomic_load(&hsrc[i], __ATOMIC_RELAXED, __HIP_MEMORY_SCOPE_AGENT);
    __syncthreads();
    float acc = 0.f;
#pragma unroll
    for (int k = 0; k < CPT; k += 4) {
      float4 hv = *(const float4*)&h_lds[chunk * CPT + k];
      acc += wreg[k] * hv.x + wreg[k + 1] * hv.y + wreg[k + 2] * hv.z + wreg[k + 3] * hv.w;
    }
    part[chunk][rl] = acc;
    __syncthreads();
    if (tid < 64) {
      float z = part[0][rl] + part[1][rl] + part[2][rl] + part[3][rl] + gxv;
      float a;
      if (gate == 2) { float e = __expf(2.f * z); a = 1.f - 2.f / (e + 1.f); }
      else a = 1.f / (1.f + __expf(-z));
      float fv = __shfl(a, jl + 16, 64);
      float gv = __shfl(a, jl + 32, 64);
      float ov = __shfl(a, jl + 48, 64);
      if (rl < 16) {
        cst = fv * cst + a * gv;
        float e2 = __expf(2.f * cst);
        float th = 1.f - 2.f / (e2 + 1.f);
        float h = ov * th;
        __hip_atomic_store(&hb0[(p ^ 1) * HD + w * 16 + rl], h,
                           __ATOMIC_RELAXED, __HIP_MEMORY_SCOPE_AGENT);
        out[(size_t)t * os + dir * HD + w * 16 + rl] = h;
      }
    }
    __syncthreads();
    if (tid == 0)
      __hip_atomic_fetch_add(&ctr[dir], 1u, __ATOMIC_RELEASE, __HIP_MEMORY_SCOPE_AGENT);
    target += (unsigned)NWG;
  }
}

// ---------------- attention key row 0: attn0 = W_attn @ ings[0] + b_attn ----------------
__global__ __launch_bounds__(256) void k_attn0(const float* __restrict__ W, const float* __restrict__ b,
                                               const float* __restrict__ ings, float* __restrict__ attn0) {
  __shared__ __align__(16) float x[1024];
  int tid = threadIdx.x;
  for (int i = tid; i < 1024; i += 256) x[i] = ings[i];  // row 0 only
  __syncthreads();
  int k = blockIdx.x * 256 + tid;
  float acc = b[k];
  const float* wr = W + (size_t)k * 1024;
  for (int d2 = 0; d2 < 1024; d2 += 4) {
    float4 wv = *(const float4*)(wr + d2);
    float4 xv = *(const float4*)&x[d2];
    acc += wv.x * xv.x + wv.y * xv.y + wv.z * xv.z + wv.w * xv.w;
  }
  attn0[k] = acc;
}

// ---------------- scores0[t] = dot(lstm_out[t], attn0) ----------------
__global__ __launch_bounds__(256) void k_scores(const float* __restrict__ lo, const float* __restrict__ attn0,
                                                float* __restrict__ sc) {
  int t = blockIdx.x * 4 + (threadIdx.x >> 6);
  int lane = threadIdx.x & 63;
  const float* row = lo + (size_t)t * 1024;
  float acc = 0.f;
  for (int k = lane * 4; k < 1024; k += 256) {
    float4 a = *(const float4*)(row + k);
    float4 b = *(const float4*)(attn0 + k);
    acc += a.x * b.x + a.y * b.y + a.z * b.z + a.w * b.w;
  }
#pragma unroll
  for (int o = 32; o; o >>= 1) acc += __shfl_xor(acc, o, 64);
  if (lane == 0) sc[t] = acc;
}

// ---------------- per-segment softmax + weighted sum of lstm_out ----------------
__global__ __launch_bounds__(256) void k_seg(const float* __restrict__ scores, const float* __restrict__ lstm_out,
                                             const int* __restrict__ indices, float* __restrict__ sf) {
  int s = blockIdx.x;
  int start = indices[s] + 1, end = indices[s + 1] + 1;
  int len = end - start;
  __shared__ __align__(16) float wls[1024];
  __shared__ float red[4];
  int tid = threadIdx.x, lane = tid & 63, wid = tid >> 6;
  float mx = -1e30f;
  for (int i = tid; i < len; i += 256) { float v = scores[start + i]; wls[i] = v; mx = fmaxf(mx, v); }
#pragma unroll
  for (int o = 32; o; o >>= 1) mx = fmaxf(mx, __shfl_xor(mx, o, 64));
  if (lane == 0) red[wid] = mx;
  __syncthreads();
  mx = fmaxf(fmaxf(red[0], red[1]), fmaxf(red[2], red[3]));
  __syncthreads();
  float sm = 0.f;
  for (int i = tid; i < len; i += 256) { float e = __expf(wls[i] - mx); wls[i] = e; sm += e; }
#pragma unroll
  for (int o = 32; o; o >>= 1) sm += __shfl_xor(sm, o, 64);
  if (lane == 0) red[wid] = sm;
  __syncthreads();
  sm = red[0] + red[1] + red[2] + red[3];
  float inv = 1.f / sm;
  float4 acc = {0.f, 0.f, 0.f, 0.f};
  int d = tid * 4;
  for (int i = 0; i < len; ++i) {
    float wv = wls[i] * inv;
    float4 v = *(const float4*)&lstm_out[(size_t)(start + i) * 1024 + d];
    acc.x += wv * v.x; acc.y += wv * v.y; acc.z += wv * v.z; acc.w += wv * v.w;
  }
  *(float4*)&sf[(size_t)s * 1024 + d] = acc;
}

// ---------------- entity input projection: gxe[s][n] (fp32, K=1024) ----------------
__global__ __launch_bounds__(256) void k_entgx(const float* __restrict__ sf,
                                               const float* __restrict__ Wf, const float* __restrict__ bf,
                                               const float* __restrict__ Wb, const float* __restrict__ bb,
                                               float* __restrict__ gxe) {
  int s = blockIdx.x, nb = blockIdx.y, tid = threadIdx.x;
  __shared__ __align__(16) float x[1024];
  for (int i = tid; i < 1024; i += 256) x[i] = sf[(size_t)s * 1024 + i];
  __syncthreads();
  int n = nb * 256 + tid;
  const float* W; float bias;
  if (n < 1024) { W = Wf + (size_t)n * 1024; bias = bf[n]; }
  else { W = Wb + (size_t)(n - 1024) * 1024; bias = bb[n - 1024]; }
  float acc = bias;
  for (int d2 = 0; d2 < 1024; d2 += 4) {
    float4 wv = *(const float4*)(W + d2);
    float4 xv = *(const float4*)&x[d2];
    acc += wv.x * xv.x + wv.y * xv.y + wv.z * xv.z + wv.w * xv.w;
  }
  gxe[(size_t)s * 2048 + n] = acc;
}

// ---------------- logits = ent @ W_log.T + b_log ----------------
__global__ __launch_bounds__(128) void k_logits(const float* __restrict__ ent, const float* __restrict__ W,
                                                const float* __restrict__ b, float* __restrict__ out) {
  int tid = threadIdx.x;
  int s = tid >> 1, m = tid & 1;
  float acc = b[m];
  const float* e = ent + (size_t)s * 512;
  const float* w = W + (size_t)m * 512;
  for (int k = 0; k < 512; k += 4) {
    float4 ev = *(const float4*)(e + k);
    float4 wv = *(const float4*)(w + k);
    acc += ev.x * wv.x + ev.y * wv.y + ev.z * wv.z + ev.w * wv.w;
  }
  out[s * 2 + m] = acc;
}

extern "C" void kernel_launch(void* const* d_in, const int* in_sizes, int n_in,
                              void* d_out, int out_size, void* d_ws, size_t ws_size,
                              hipStream_t stream) {
  const float* elmo_sent = (const float*)d_in[0];
  const float* elmo_ings = (const float*)d_in[1];
  const int* indices = (const int*)d_in[2];
  const float* Wih_f = (const float*)d_in[3];
  const float* Whh_f = (const float*)d_in[4];
  const float* b_f = (const float*)d_in[5];
  const float* Wih_b = (const float*)d_in[6];
  const float* Whh_b = (const float*)d_in[7];
  const float* b_b = (const float*)d_in[8];
  const float* h0_sent = (const float*)d_in[9];
  const float* c0_sent = (const float*)d_in[10];
  const float* W_attn = (const float*)d_in[11];
  const float* b_attn = (const float*)d_in[12];
  const float* Wih_ef = (const float*)d_in[13];
  const float* Whh_ef = (const float*)d_in[14];
  const float* b_ef = (const float*)d_in[15];
  const float* Wih_eb = (const float*)d_in[16];
  const float* Whh_eb = (const float*)d_in[17];
  const float* b_eb = (const float*)d_in[18];
  const float* h0_ent = (const float*)d_in[19];
  const float* c0_ent = (const float*)d_in[20];
  const float* W_log = (const float*)d_in[21];
  const float* b_log = (const float*)d_in[22];

  const int T = 8192;

  char* ws = (char*)d_ws;
  size_t off = 0;
  auto alloc = [&](size_t bytes) { void* p = ws + off; off = WS_ALIGN(off + bytes); return p; };
  unsigned short* Xh = (unsigned short*)alloc((size_t)T * 1024 * 2);
  unsigned short* Xl = (unsigned short*)alloc((size_t)T * 1024 * 2);
  unsigned short* Wch = (unsigned short*)alloc((size_t)4096 * 1024 * 2);
  unsigned short* Wcl = (unsigned short*)alloc((size_t)4096 * 1024 * 2);
  float* bc = (float*)alloc(4096 * 4);
  float* gx = (float*)alloc((size_t)T * 4096 * 4);
  float* lstm_out = (float*)alloc((size_t)T * 1024 * 4);
  float* attn0 = (float*)alloc(1024 * 4);
  float* scores0 = (float*)alloc((size_t)T * 4);
  float* sf = (float*)alloc(64 * 1024 * 4);
  float* gxe = (float*)alloc(64 * 2048 * 4);
  float* ent = (float*)alloc(64 * 512 * 4);
  float* hbuf = (float*)alloc(2 * 2 * 512 * 4);
  float* hbufe = (float*)alloc(2 * 2 * 256 * 4);
  unsigned* ctrs = (unsigned*)alloc(256);

  hipMemsetAsync(ctrs, 0, 256, stream);

  k_split_bf16<<<1024, 256, 0, stream>>>(elmo_sent, Xh, Xl, (size_t)T * 1024);
  k_split_bf16<<<512, 256, 0, stream>>>(Wih_f, Wch, Wcl, (size_t)2048 * 1024);
  k_split_bf16<<<512, 256, 0, stream>>>(Wih_b, Wch + (size_t)2048 * 1024, Wcl + (size_t)2048 * 1024,
                                        (size_t)2048 * 1024);
  k_concat2<<<16, 256, 0, stream>>>(b_f, b_b, 2048, 2048, bc);

  dim3 g1(8192 / 128, 4096 / 128);
  k_gemm_split<<<g1, 256, 0, stream>>>(Xh, Xl, Wch, Wcl, bc, gx, 8192, 4096, 1024);

  k_attn0<<<4, 256, 0, stream>>>(W_attn, b_attn, elmo_ings, attn0);

  k_lstm_rec<512><<<64, 256, 0, stream>>>(gx, 4096, Whh_f, Whh_b, h0_sent, c0_sent,
                                          lstm_out, 1024, hbuf, ctrs, T, 32);

  k_scores<<<T / 4, 256, 0, stream>>>(lstm_out, attn0, scores0);

  k_seg<<<64, 256, 0, stream>>>(scores0, lstm_out, indices, sf);

  dim3 g2(64, 8);
  k_entgx<<<g2, 256, 0, stream>>>(sf, Wih_ef, b_ef, Wih_eb, b_eb, gxe);

  k_lstm_rec<256><<<32, 256, 0, stream>>>(gxe, 2048, Whh_ef, Whh_eb, h0_ent, c0_ent,
                                          ent, 512, hbufe, ctrs + 2, 64, 16);

  k_logits<<<1, 128, 0, stream>>>(ent, W_log, b_log, (float*)d_out);
}

// Round 2
// 16964.165 us; speedup vs baseline: 1.7137x; 1.7137x over previous
//
#include <hip/hip_runtime.h>

typedef __attribute__((ext_vector_type(8))) short short8;
typedef __attribute__((ext_vector_type(4))) float f32x4;

#define WS_ALIGN(x) (((x) + 255) & ~(size_t)255)

__device__ __forceinline__ unsigned short f2bf_rne(float f) {
  union { float f; unsigned u; } v; v.f = f;
  unsigned r = v.u + 0x7fffu + ((v.u >> 16) & 1u);
  return (unsigned short)(r >> 16);
}

// ---------------- conversion: f32 -> (hi bf16, lo bf16) split ----------------
__global__ __launch_bounds__(256) void k_split_bf16(const float* __restrict__ in,
                                                    unsigned short* __restrict__ hi,
                                                    unsigned short* __restrict__ lo, size_t n) {
  size_t i = (size_t)blockIdx.x * 256 + threadIdx.x;
  size_t stride = (size_t)gridDim.x * 256;
  for (; i < n; i += stride) {
    float x = in[i];
    unsigned short h = f2bf_rne(x);
    union { unsigned u; float f; } hv; hv.u = (unsigned)h << 16;
    hi[i] = h;
    lo[i] = f2bf_rne(x - hv.f);
  }
}

__global__ void k_concat2(const float* __restrict__ a, const float* __restrict__ b,
                          int na, int nb, float* __restrict__ o) {
  int i = blockIdx.x * 256 + threadIdx.x;
  if (i < na) o[i] = a[i];
  else if (i < na + nb) o[i] = b[i - na];
}

// ---------------- split-bf16 MFMA GEMM: C[m][n] = sum_k A[m][k]*B[n][k] + bias[n] ----------------
__global__ __launch_bounds__(256) void k_gemm_split(
    const unsigned short* __restrict__ Ah, const unsigned short* __restrict__ Al,
    const unsigned short* __restrict__ Bh, const unsigned short* __restrict__ Bl,
    const float* __restrict__ bias, float* __restrict__ C,
    int M, int N, int K) {
  __shared__ __align__(16) unsigned short sAh[128][40];
  __shared__ __align__(16) unsigned short sAl[128][40];
  __shared__ __align__(16) unsigned short sBh[128][40];
  __shared__ __align__(16) unsigned short sBl[128][40];
  int bm = blockIdx.x, bn = blockIdx.y;
  int tid = threadIdx.x;
  int lane = tid & 63, wave = tid >> 6;
  int wm = wave >> 1, wn = wave & 1;
  int lr = lane & 15, lk = (lane >> 4) * 8;
  f32x4 acc[4][4] = {};
  for (int k0 = 0; k0 < K; k0 += 32) {
    __syncthreads();
#pragma unroll
    for (int i = 0; i < 2; ++i) {
      int q = tid + i * 256;
      int row = q >> 2, c8 = (q & 3) * 8;
      size_t ga = (size_t)(bm * 128 + row) * K + k0 + c8;
      size_t gb = (size_t)(bn * 128 + row) * K + k0 + c8;
      *(short8*)&sAh[row][c8] = *(const short8*)(Ah + ga);
      *(short8*)&sAl[row][c8] = *(const short8*)(Al + ga);
      *(short8*)&sBh[row][c8] = *(const short8*)(Bh + gb);
      *(short8*)&sBl[row][c8] = *(const short8*)(Bl + gb);
    }
    __syncthreads();
    short8 ah[4], al[4], bh[4], bl[4];
#pragma unroll
    for (int x = 0; x < 4; ++x) {
      ah[x] = *(const short8*)&sAh[wm * 64 + x * 16 + lr][lk];
      al[x] = *(const short8*)&sAl[wm * 64 + x * 16 + lr][lk];
      bh[x] = *(const short8*)&sBh[wn * 64 + x * 16 + lr][lk];
      bl[x] = *(const short8*)&sBl[wn * 64 + x * 16 + lr][lk];
    }
#pragma unroll
    for (int mi = 0; mi < 4; ++mi)
#pragma unroll
      for (int ni = 0; ni < 4; ++ni) {
        acc[mi][ni] = __builtin_amdgcn_mfma_f32_16x16x32_bf16(ah[mi], bh[ni], acc[mi][ni], 0, 0, 0);
        acc[mi][ni] = __builtin_amdgcn_mfma_f32_16x16x32_bf16(ah[mi], bl[ni], acc[mi][ni], 0, 0, 0);
        acc[mi][ni] = __builtin_amdgcn_mfma_f32_16x16x32_bf16(al[mi], bh[ni], acc[mi][ni], 0, 0, 0);
      }
  }
#pragma unroll
  for (int mi = 0; mi < 4; ++mi)
#pragma unroll
    for (int ni = 0; ni < 4; ++ni) {
      int r0 = bm * 128 + wm * 64 + mi * 16 + (lane >> 4) * 4;
      int c = bn * 128 + wn * 64 + ni * 16 + lr;
      float bv = bias[c];
#pragma unroll
      for (int r = 0; r < 4; ++r)
        C[(size_t)(r0 + r) * N + c] = acc[mi][ni][r] + bv;
    }
}

// ---------------- LSTM recurrence v2: tag-in-data publish, replicated h buffer ----------------
// grid = 2*NWG blocks of 256 threads. WG w of direction d owns hidden units [w*16, w*16+16).
// Wave v (0..3) of the WG owns units [w*16+v*4, +4) fully: 16 gate rows, each row's
// K-dot split over 4 lanes (CPT = HD/4 weights per lane, held in VGPRs).
// h published as (f32,h | u32,tag) 64-bit words into R replicas; consumers poll their
// replica directly. One __syncthreads per step. Double-buffered; tags memset to 0
// at launch (expected tags are 1..T+1, so stale/poisoned words never match).
template <int HD, int NWG>
__global__ __launch_bounds__(256, 1) void k_lstm_rec2(
    const float* __restrict__ gx, int gxs,
    const float* __restrict__ Whh_f, const float* __restrict__ Whh_b,
    const float* __restrict__ h0, const float* __restrict__ c0,
    float* __restrict__ out, int os,
    unsigned long long* hbuf, int T) {
  constexpr int CPT = HD / 4;
  constexpr int R = 8;
  constexpr int W = HD / 256;  // words polled per thread (2 for HD=512, 1 for HD=256)
  int tid = threadIdx.x;
  int wg = blockIdx.x;
  int dir = (wg >= NWG) ? 1 : 0;
  int w = wg - dir * NWG;
  int lane = tid & 63;
  int v = tid >> 6;
  int r = lane & 15;
  int kc = lane >> 4;
  int g = r >> 2, uu = r & 3;
  int unit = w * 16 + v * 4 + uu;
  const float* Whh = dir ? Whh_b : Whh_f;

  float wreg[CPT];
  {
    const float* wp = Whh + ((size_t)g * HD + unit) * HD + kc * CPT;
#pragma unroll
    for (int k = 0; k < CPT; k += 4) {
      float4 x = *(const float4*)(wp + k);
      wreg[k] = x.x; wreg[k + 1] = x.y; wreg[k + 2] = x.z; wreg[k + 3] = x.w;
    }
  }

  __shared__ __align__(16) float h_lds[HD];

  unsigned long long* hb0 = hbuf + (size_t)dir * 2 * R * HD;

  float cst = 0.f;
  if (lane < 4) cst = c0[dir * HD + w * 16 + v * 4 + lane];

  // init publish: h0 with tag 1 into buffer p=0, all replicas
  {
    float hval = (lane < 4) ? h0[dir * HD + w * 16 + v * 4 + lane] : 0.f;
    float hb = __shfl(hval, lane & 3, 64);
    if (lane < 4 * R) {
      int rep = lane >> 2;
      int un = w * 16 + v * 4 + (lane & 3);
      unsigned long long pk = (1ull << 32) | (unsigned long long)__float_as_uint(hb);
      __hip_atomic_store(&hb0[(size_t)rep * HD + un], pk, __ATOMIC_RELAXED,
                         __HIP_MEMORY_SCOPE_AGENT);
    }
  }

  int myrep = w & (R - 1);
  for (int ti = 0; ti < T; ++ti) {
    int t = dir ? (T - 1 - ti) : ti;
    unsigned tag = (unsigned)ti + 1u;
    int p = ti & 1;
    // issue gx load early; its latency hides under the poll
    float gxv = gx[(size_t)t * gxs + (size_t)dir * 4 * HD + (size_t)g * HD + unit];
    // poll this step's h words (one coherence round-trip in the common case)
    const unsigned long long* src = hb0 + ((size_t)p * R + myrep) * HD;
    unsigned long long xv[W];
#pragma unroll
    for (int q = 0; q < W; ++q)
      xv[q] = __hip_atomic_load(&src[tid + q * 256], __ATOMIC_RELAXED, __HIP_MEMORY_SCOPE_AGENT);
#pragma unroll
    for (int q = 0; q < W; ++q) {
      while ((unsigned)(xv[q] >> 32) != tag)
        xv[q] = __hip_atomic_load(&src[tid + q * 256], __ATOMIC_RELAXED, __HIP_MEMORY_SCOPE_AGENT);
      h_lds[tid + q * 256] = __uint_as_float((unsigned)(xv[q] & 0xffffffffu));
    }
    __syncthreads();
    // per-lane K-chunk dot
    float acc = 0.f;
#pragma unroll
    for (int k = 0; k < CPT; k += 4) {
      float4 hv = *(const float4*)&h_lds[kc * CPT + k];
      acc += wreg[k] * hv.x + wreg[k + 1] * hv.y + wreg[k + 2] * hv.z + wreg[k + 3] * hv.w;
    }
    acc += __shfl_xor(acc, 16, 64);
    acc += __shfl_xor(acc, 32, 64);
    // gate activations in lanes 0..15 (row r = g*4+uu)
    float a = 0.f;
    {
      float z = acc + gxv;
      if (g == 2) { float e = __expf(2.f * z); a = 1.f - 2.f / (e + 1.f); }
      else a = 1.f / (1.f + __expf(-z));
    }
    // gather i,f,g,o for unit (lane&3) and update state in lanes 0..3
    float ivv = __shfl(a, (lane & 3), 64);
    float fv = __shfl(a, 4 + (lane & 3), 64);
    float gv = __shfl(a, 8 + (lane & 3), 64);
    float ov = __shfl(a, 12 + (lane & 3), 64);
    float hnew = 0.f;
    if (lane < 4) {
      cst = fv * cst + ivv * gv;
      float e2 = __expf(2.f * cst);
      float th = 1.f - 2.f / (e2 + 1.f);
      hnew = ov * th;
      out[(size_t)t * os + dir * HD + w * 16 + v * 4 + lane] = hnew;
    }
    // publish h for next step into buffer p^1, all replicas
    float hb = __shfl(hnew, lane & 3, 64);
    if (lane < 4 * R) {
      int rep = lane >> 2;
      int un = w * 16 + v * 4 + (lane & 3);
      unsigned long long pk = ((unsigned long long)(tag + 1u) << 32) |
                              (unsigned long long)__float_as_uint(hb);
      __hip_atomic_store(&hb0[((size_t)(p ^ 1) * R + rep) * HD + un], pk,
                         __ATOMIC_RELAXED, __HIP_MEMORY_SCOPE_AGENT);
    }
  }
}

// ---------------- attention key row 0: attn0 = W_attn @ ings[0] + b_attn ----------------
__global__ __launch_bounds__(256) void k_attn0(const float* __restrict__ W, const float* __restrict__ b,
                                               const float* __restrict__ ings, float* __restrict__ attn0) {
  __shared__ __align__(16) float x[1024];
  int tid = threadIdx.x;
  for (int i = tid; i < 1024; i += 256) x[i] = ings[i];  // row 0 only
  __syncthreads();
  int k = blockIdx.x * 256 + tid;
  float acc = b[k];
  const float* wr = W + (size_t)k * 1024;
  for (int d2 = 0; d2 < 1024; d2 += 4) {
    float4 wv = *(const float4*)(wr + d2);
    float4 xv = *(const float4*)&x[d2];
    acc += wv.x * xv.x + wv.y * xv.y + wv.z * xv.z + wv.w * xv.w;
  }
  attn0[k] = acc;
}

// ---------------- scores0[t] = dot(lstm_out[t], attn0) ----------------
__global__ __launch_bounds__(256) void k_scores(const float* __restrict__ lo, const float* __restrict__ attn0,
                                                float* __restrict__ sc) {
  int t = blockIdx.x * 4 + (threadIdx.x >> 6);
  int lane = threadIdx.x & 63;
  const float* row = lo + (size_t)t * 1024;
  float acc = 0.f;
  for (int k = lane * 4; k < 1024; k += 256) {
    float4 a = *(const float4*)(row + k);
    float4 b = *(const float4*)(attn0 + k);
    acc += a.x * b.x + a.y * b.y + a.z * b.z + a.w * b.w;
  }
#pragma unroll
  for (int o = 32; o; o >>= 1) acc += __shfl_xor(acc, o, 64);
  if (lane == 0) sc[t] = acc;
}

// ---------------- per-segment softmax + weighted sum of lstm_out ----------------
__global__ __launch_bounds__(256) void k_seg(const float* __restrict__ scores, const float* __restrict__ lstm_out,
                                             const int* __restrict__ indices, float* __restrict__ sf) {
  int s = blockIdx.x;
  int start = indices[s] + 1, end = indices[s + 1] + 1;
  int len = end - start;
  __shared__ __align__(16) float wls[1024];
  __shared__ float red[4];
  int tid = threadIdx.x, lane = tid & 63, wid = tid >> 6;
  float mx = -1e30f;
  for (int i = tid; i < len; i += 256) { float v = scores[start + i]; wls[i] = v; mx = fmaxf(mx, v); }
#pragma unroll
  for (int o = 32; o; o >>= 1) mx = fmaxf(mx, __shfl_xor(mx, o, 64));
  if (lane == 0) red[wid] = mx;
  __syncthreads();
  mx = fmaxf(fmaxf(red[0], red[1]), fmaxf(red[2], red[3]));
  __syncthreads();
  float sm = 0.f;
  for (int i = tid; i < len; i += 256) { float e = __expf(wls[i] - mx); wls[i] = e; sm += e; }
#pragma unroll
  for (int o = 32; o; o >>= 1) sm += __shfl_xor(sm, o, 64);
  if (lane == 0) red[wid] = sm;
  __syncthreads();
  sm = red[0] + red[1] + red[2] + red[3];
  float inv = 1.f / sm;
  float4 acc = {0.f, 0.f, 0.f, 0.f};
  int d = tid * 4;
  for (int i = 0; i < len; ++i) {
    float wv = wls[i] * inv;
    float4 v = *(const float4*)&lstm_out[(size_t)(start + i) * 1024 + d];
    acc.x += wv * v.x; acc.y += wv * v.y; acc.z += wv * v.z; acc.w += wv * v.w;
  }
  *(float4*)&sf[(size_t)s * 1024 + d] = acc;
}

// ---------------- entity input projection: gxe[s][n] (fp32, K=1024) ----------------
__global__ __launch_bounds__(256) void k_entgx(const float* __restrict__ sf,
                                               const float* __restrict__ Wf, const float* __restrict__ bf,
                                               const float* __restrict__ Wb, const float* __restrict__ bb,
                                               float* __restrict__ gxe) {
  int s = blockIdx.x, nb = blockIdx.y, tid = threadIdx.x;
  __shared__ __align__(16) float x[1024];
  for (int i = tid; i < 1024; i += 256) x[i] = sf[(size_t)s * 1024 + i];
  __syncthreads();
  int n = nb * 256 + tid;
  const float* W; float bias;
  if (n < 1024) { W = Wf + (size_t)n * 1024; bias = bf[n]; }
  else { W = Wb + (size_t)(n - 1024) * 1024; bias = bb[n - 1024]; }
  float acc = bias;
  for (int d2 = 0; d2 < 1024; d2 += 4) {
    float4 wv = *(const float4*)(W + d2);
    float4 xv = *(const float4*)&x[d2];
    acc += wv.x * xv.x + wv.y * xv.y + wv.z * xv.z + wv.w * xv.w;
  }
  gxe[(size_t)s * 2048 + n] = acc;
}

// ---------------- logits = ent @ W_log.T + b_log ----------------
__global__ __launch_bounds__(128) void k_logits(const float* __restrict__ ent, const float* __restrict__ W,
                                                const float* __restrict__ b, float* __restrict__ out) {
  int tid = threadIdx.x;
  int s = tid >> 1, m = tid & 1;
  float acc = b[m];
  const float* e = ent + (size_t)s * 512;
  const float* w = W + (size_t)m * 512;
  for (int k = 0; k < 512; k += 4) {
    float4 ev = *(const float4*)(e + k);
    float4 wv = *(const float4*)(w + k);
    acc += ev.x * wv.x + ev.y * wv.y + ev.z * wv.z + ev.w * wv.w;
  }
  out[s * 2 + m] = acc;
}

extern "C" void kernel_launch(void* const* d_in, const int* in_sizes, int n_in,
                              void* d_out, int out_size, void* d_ws, size_t ws_size,
                              hipStream_t stream) {
  const float* elmo_sent = (const float*)d_in[0];
  const float* elmo_ings = (const float*)d_in[1];
  const int* indices = (const int*)d_in[2];
  const float* Wih_f = (const float*)d_in[3];
  const float* Whh_f = (const float*)d_in[4];
  const float* b_f = (const float*)d_in[5];
  const float* Wih_b = (const float*)d_in[6];
  const float* Whh_b = (const float*)d_in[7];
  const float* b_b = (const float*)d_in[8];
  const float* h0_sent = (const float*)d_in[9];
  const float* c0_sent = (const float*)d_in[10];
  const float* W_attn = (const float*)d_in[11];
  const float* b_attn = (const float*)d_in[12];
  const float* Wih_ef = (const float*)d_in[13];
  const float* Whh_ef = (const float*)d_in[14];
  const float* b_ef = (const float*)d_in[15];
  const float* Wih_eb = (const float*)d_in[16];
  const float* Whh_eb = (const float*)d_in[17];
  const float* b_eb = (const float*)d_in[18];
  const float* h0_ent = (const float*)d_in[19];
  const float* c0_ent = (const float*)d_in[20];
  const float* W_log = (const float*)d_in[21];
  const float* b_log = (const float*)d_in[22];

  const int T = 8192;

  char* ws = (char*)d_ws;
  size_t off = 0;
  auto alloc = [&](size_t bytes) { void* p = ws + off; off = WS_ALIGN(off + bytes); return p; };
  unsigned short* Xh = (unsigned short*)alloc((size_t)T * 1024 * 2);
  unsigned short* Xl = (unsigned short*)alloc((size_t)T * 1024 * 2);
  unsigned short* Wch = (unsigned short*)alloc((size_t)4096 * 1024 * 2);
  unsigned short* Wcl = (unsigned short*)alloc((size_t)4096 * 1024 * 2);
  float* bc = (float*)alloc(4096 * 4);
  float* gx = (float*)alloc((size_t)T * 4096 * 4);
  float* lstm_out = (float*)alloc((size_t)T * 1024 * 4);
  float* attn0 = (float*)alloc(1024 * 4);
  float* scores0 = (float*)alloc((size_t)T * 4);
  float* sf = (float*)alloc(64 * 1024 * 4);
  float* gxe = (float*)alloc(64 * 2048 * 4);
  float* ent = (float*)alloc(64 * 512 * 4);
  // tagged, replicated h buffers: [dir][2][R=8][HD] x 8B
  unsigned long long* hbuf = (unsigned long long*)alloc((size_t)2 * 2 * 8 * 512 * 8);
  unsigned long long* hbufe = (unsigned long long*)alloc((size_t)2 * 2 * 8 * 256 * 8);

  // zero tags each launch (expected tags 1..T+1 never match 0 or stale 0xAA poison)
  hipMemsetAsync(hbuf, 0, (size_t)2 * 2 * 8 * 512 * 8, stream);
  hipMemsetAsync(hbufe, 0, (size_t)2 * 2 * 8 * 256 * 8, stream);

  k_split_bf16<<<1024, 256, 0, stream>>>(elmo_sent, Xh, Xl, (size_t)T * 1024);
  k_split_bf16<<<512, 256, 0, stream>>>(Wih_f, Wch, Wcl, (size_t)2048 * 1024);
  k_split_bf16<<<512, 256, 0, stream>>>(Wih_b, Wch + (size_t)2048 * 1024, Wcl + (size_t)2048 * 1024,
                                        (size_t)2048 * 1024);
  k_concat2<<<16, 256, 0, stream>>>(b_f, b_b, 2048, 2048, bc);

  dim3 g1(8192 / 128, 4096 / 128);
  k_gemm_split<<<g1, 256, 0, stream>>>(Xh, Xl, Wch, Wcl, bc, gx, 8192, 4096, 1024);

  k_attn0<<<4, 256, 0, stream>>>(W_attn, b_attn, elmo_ings, attn0);

  k_lstm_rec2<512, 32><<<64, 256, 0, stream>>>(gx, 4096, Whh_f, Whh_b, h0_sent, c0_sent,
                                               lstm_out, 1024, hbuf, T);

  k_scores<<<T / 4, 256, 0, stream>>>(lstm_out, attn0, scores0);

  k_seg<<<64, 256, 0, stream>>>(scores0, lstm_out, indices, sf);

  dim3 g2(64, 8);
  k_entgx<<<g2, 256, 0, stream>>>(sf, Wih_ef, b_ef, Wih_eb, b_eb, gxe);

  k_lstm_rec2<256, 16><<<32, 256, 0, stream>>>(gxe, 2048, Whh_ef, Whh_eb, h0_ent, c0_ent,
                                               ent, 512, hbufe, 64);

  k_logits<<<1, 128, 0, stream>>>(ent, W_log, b_log, (float*)d_out);
}